// Round 1
// baseline (1639.588 us; speedup 1.0000x reference)
//
#include <hip/hip_runtime.h>
#include <stdint.h>

// MoE top-2 SwiGLU FFN, MI355X. fp32 in/out, bf16 MFMA compute.
// B=4 S=2048 H=1024 F=4096 E=8 K=2 -> T=8192 tokens, 16384 pairs.

#define Hdim 1024
#define Fdim 4096
#define NE 8
#define NT 8192
#define NPAIR 16384
#define OUT0 (NT * Hdim)   // 8388608 floats, then router_logits [NT,8]

typedef unsigned short u16;
typedef __bf16 bf16x8 __attribute__((ext_vector_type(8)));
typedef unsigned short u16x8 __attribute__((ext_vector_type(8)));
typedef float f32x4 __attribute__((ext_vector_type(4)));

// ---- workspace layout (bytes) ----
#define WS_HDR      0ull
#define WS_TOKTOP   4096ull
#define WS_TOKW     69632ull
#define WS_ROWTOK   135168ull
#define WS_ROWW     200704ull
#define WS_XG       266240ull          // bf16 [16384][1024]
#define WS_WG       33820672ull        // packed bf16 [8][32][32][128][32]
#define WS_WU       100929536ull
#define WS_WD       168038400ull       // packed bf16 [8][8][128][128][32]
#define WS_ACT      235147264ull       // bf16 [16384][4096]
#define WS_NEEDED   369364992ull

// hdr int indices
#define HDR_CNT 0
#define HDR_OFF 8
#define HDR_CUR 16
#define HDR_TOTALM 24
#define HDR_BEXP 32      // 160 slots
#define HDR_BSTART 192
#define HDR_BCNT 352

__device__ __forceinline__ u16 f2bf(float f) {
  union { float f; unsigned int u; } v; v.f = f;
  unsigned int u = v.u;
  u += 0x7fffu + ((u >> 16) & 1u);   // round-to-nearest-even
  return (u16)(u >> 16);
}

// async global->LDS, 16B per lane. lds base must be wave-uniform; HW adds lane*16.
__device__ __forceinline__ void gl2lds16(const void* g, void* l) {
  __builtin_amdgcn_global_load_lds(
      (__attribute__((address_space(1))) void*)(uintptr_t)g,
      (__attribute__((address_space(3))) void*)(uint32_t)(uintptr_t)l,
      16, 0, 0);
}

__global__ void k_sentinel(float* out) { out[0] = 3.0e8f; }

// ---- pack: fp32 [K][N] -> bf16 tiles [nb][kb][128][32], contiguous 8KB each ----
__global__ void k_pack(const float* __restrict__ wgp, const float* __restrict__ wup,
                       const float* __restrict__ wdp, u16* __restrict__ PG,
                       u16* __restrict__ PU, u16* __restrict__ PD) {
  __shared__ float lds[32 * 129];
  int tile = blockIdx.x;
  int tensor = tile >> 13;     // 8192 tiles per tensor
  int rem = tile & 8191;
  const float* src; u16* dst; int rowStride;
  int e = rem >> 10, r2 = rem & 1023;
  if (tensor == 0) {
    int nb = r2 >> 5, kb = r2 & 31;
    src = wgp + ((size_t)e * 1024 + kb * 32) * 4096 + nb * 128;
    rowStride = 4096; dst = PG + (size_t)rem * 4096 + (size_t)e * 0;
    dst = PG + ((size_t)e * 1024 + (size_t)r2) * 4096 - (size_t)r2 * 4096 + (size_t)r2 * 4096; // = PG + rem*4096
    dst = PG + (size_t)rem * 4096;
  } else if (tensor == 1) {
    int nb = r2 >> 5, kb = r2 & 31;
    src = wup + ((size_t)e * 1024 + kb * 32) * 4096 + nb * 128;
    rowStride = 4096; dst = PU + (size_t)rem * 4096;
  } else {
    int nb = r2 >> 7, kb = r2 & 127;
    src = wdp + ((size_t)e * 4096 + kb * 32) * 1024 + nb * 128;
    rowStride = 1024; dst = PD + (size_t)rem * 4096;
  }
  int tid = threadIdx.x;
  for (int h = 0; h < 4; ++h) {
    int c = tid + h * 256;          // 1024 float4 chunks
    int k = c >> 5, n = (c & 31) * 4;
    f32x4 v = *(const f32x4*)(src + (size_t)k * rowStride + n);
    lds[k * 129 + n + 0] = v[0];
    lds[k * 129 + n + 1] = v[1];
    lds[k * 129 + n + 2] = v[2];
    lds[k * 129 + n + 3] = v[3];
  }
  __syncthreads();
  for (int h = 0; h < 2; ++h) {
    int c = tid + h * 256;          // 512 16B chunks of dst
    int ni = c >> 2, ki0 = (c & 3) * 8;
    u16x8 o;
#pragma unroll
    for (int j = 0; j < 8; ++j) o[j] = f2bf(lds[(ki0 + j) * 129 + ni]);
    *(u16x8*)(dst + c * 8) = o;
  }
}

// ---- router: logits, softmax, top-2, counts ----
__global__ void k_router(const float* __restrict__ x, const float* __restrict__ wg,
                         float* __restrict__ logits, int* __restrict__ hdr,
                         int* __restrict__ tokTop, float* __restrict__ tokW) {
  int t = blockIdx.x;
  int lane = threadIdx.x;   // 64 threads
  float acc[NE] = {0.f, 0.f, 0.f, 0.f, 0.f, 0.f, 0.f, 0.f};
  const float* xr = x + (size_t)t * Hdim + lane * 16;
#pragma unroll
  for (int j4 = 0; j4 < 4; ++j4) {
    f32x4 xv = *(const f32x4*)(xr + j4 * 4);
    int k0 = lane * 16 + j4 * 4;
#pragma unroll
    for (int kk = 0; kk < 4; ++kk) {
      f32x4 w0 = *(const f32x4*)(wg + (size_t)(k0 + kk) * 8);
      f32x4 w1 = *(const f32x4*)(wg + (size_t)(k0 + kk) * 8 + 4);
      float xs = xv[kk];
      acc[0] += xs * w0[0]; acc[1] += xs * w0[1]; acc[2] += xs * w0[2]; acc[3] += xs * w0[3];
      acc[4] += xs * w1[0]; acc[5] += xs * w1[1]; acc[6] += xs * w1[2]; acc[7] += xs * w1[3];
    }
  }
#pragma unroll
  for (int off = 32; off > 0; off >>= 1)
#pragma unroll
    for (int e = 0; e < NE; ++e) acc[e] += __shfl_xor(acc[e], off, 64);
  if (lane < NE) logits[(size_t)t * NE + lane] = acc[lane];
  if (lane == 0) {
    float m = acc[0];
#pragma unroll
    for (int e = 1; e < NE; ++e) m = fmaxf(m, acc[e]);
    float p[NE];
#pragma unroll
    for (int e = 0; e < NE; ++e) p[e] = expf(acc[e] - m);
    int i1 = 0; float p1 = p[0];
#pragma unroll
    for (int e = 1; e < NE; ++e) if (p[e] > p1) { p1 = p[e]; i1 = e; }
    int i2 = -1; float p2 = -1.f;
#pragma unroll
    for (int e = 0; e < NE; ++e) if (e != i1 && p[e] > p2) { p2 = p[e]; i2 = e; }
    float s = p1 + p2;
    tokTop[t * 2] = i1; tokTop[t * 2 + 1] = i2;
    tokW[t * 2] = p1 / s; tokW[t * 2 + 1] = p2 / s;
    atomicAdd(&hdr[HDR_CNT + i1], 1);
    atomicAdd(&hdr[HDR_CNT + i2], 1);
  }
}

// ---- scan: expert offsets + M-block map (<=136 blocks) ----
__global__ void k_scan(int* hdr) {
  if (threadIdx.x != 0 || blockIdx.x != 0) return;
  int cum = 0, mb = 0;
  for (int e = 0; e < NE; ++e) {
    hdr[HDR_OFF + e] = cum;
    int c = hdr[HDR_CNT + e];
    int nb = (c + 127) >> 7;
    for (int b = 0; b < nb; ++b) {
      hdr[HDR_BEXP + mb] = e;
      hdr[HDR_BSTART + mb] = cum + b * 128;
      int rc = c - b * 128; if (rc > 128) rc = 128;
      hdr[HDR_BCNT + mb] = rc;
      ++mb;
    }
    cum += c;
  }
  hdr[HDR_TOTALM] = mb;
}

// ---- place pairs into compact per-expert segments ----
__global__ void k_place(int* __restrict__ hdr, const int* __restrict__ tokTop,
                        const float* __restrict__ tokW, int* __restrict__ rowTok,
                        float* __restrict__ rowW) {
  int t = blockIdx.x * 256 + threadIdx.x;
  if (t >= NT) return;
#pragma unroll
  for (int k = 0; k < 2; ++k) {
    int e = tokTop[t * 2 + k];
    int pos = hdr[HDR_OFF + e] + atomicAdd(&hdr[HDR_CUR + e], 1);
    rowTok[pos] = t;
    rowW[pos] = tokW[t * 2 + k];
  }
}

// ---- gather x rows -> bf16 xg[pair][1024] ----
__global__ void k_gather(const float* __restrict__ x, const int* __restrict__ rowTok,
                         u16* __restrict__ xg) {
  int wid = threadIdx.x >> 6, lane = threadIdx.x & 63;
  int p = blockIdx.x * 4 + wid;
  int tok = rowTok[p];
  const float* src = x + (size_t)tok * Hdim;
  u16* dst = xg + (size_t)p * Hdim;
#pragma unroll
  for (int it = 0; it < 2; ++it) {
    int b = it * 512 + lane * 8;
    f32x4 a = *(const f32x4*)(src + b);
    f32x4 c = *(const f32x4*)(src + b + 4);
    u16x8 o;
    o[0] = f2bf(a[0]); o[1] = f2bf(a[1]); o[2] = f2bf(a[2]); o[3] = f2bf(a[3]);
    o[4] = f2bf(c[0]); o[5] = f2bf(c[1]); o[6] = f2bf(c[2]); o[7] = f2bf(c[3]);
    *(u16x8*)(dst + b) = o;
  }
}

// ---- GEMM1: [rows,1024]x[1024,128] dual (gate & up), fused SiLU*up -> act bf16 ----
__global__ __launch_bounds__(256) void k_gemm1(
    const u16* __restrict__ xg, const u16* __restrict__ PG, const u16* __restrict__ PU,
    const int* __restrict__ hdr, u16* __restrict__ act) {
  __shared__ u16 ldsA[128 * 32];
  __shared__ u16 ldsG[128 * 32];
  __shared__ u16 ldsU[128 * 32];
  int m = blockIdx.y;
  if (m >= hdr[HDR_TOTALM]) return;
  int e = hdr[HDR_BEXP + m], rowStart = hdr[HDR_BSTART + m], rowCnt = hdr[HDR_BCNT + m];
  int nb = blockIdx.x;           // 0..31 over F
  int tid = threadIdx.x, lane = tid & 63, wid = tid >> 6;
  int wm = (wid & 1) * 64, wn = (wid >> 1) * 64;
  const u16* gT = PG + (((size_t)e * 32 + nb) * 32) * 4096;
  const u16* uT = PU + (((size_t)e * 32 + nb) * 32) * 4096;
  f32x4 ag[4][4] = {};
  f32x4 au[4][4] = {};
  int rA = lane & 15, kA = (lane >> 4) * 8;
  for (int kb = 0; kb < 32; ++kb) {
#pragma unroll
    for (int h = 0; h < 2; ++h) {
      int c = wid * 64 + lane + h * 256;     // 512 16B chunks per tile
      int row = c >> 2, seg = c & 3;
      int p = rowStart + row; if (p > NPAIR - 1) p = NPAIR - 1;
      gl2lds16(xg + (size_t)p * 1024 + kb * 32 + seg * 8, ldsA + (wid * 64 + h * 256) * 8);
      gl2lds16(gT + (size_t)kb * 4096 + (size_t)c * 8, ldsG + (wid * 64 + h * 256) * 8);
      gl2lds16(uT + (size_t)kb * 4096 + (size_t)c * 8, ldsU + (wid * 64 + h * 256) * 8);
    }
    __syncthreads();
    bf16x8 a[4], bg[4], bu[4];
#pragma unroll
    for (int i = 0; i < 4; ++i)
      a[i] = __builtin_bit_cast(bf16x8, *(const u16x8*)&ldsA[(wm + i * 16 + rA) * 32 + kA]);
#pragma unroll
    for (int j = 0; j < 4; ++j) {
      bg[j] = __builtin_bit_cast(bf16x8, *(const u16x8*)&ldsG[(wn + j * 16 + rA) * 32 + kA]);
      bu[j] = __builtin_bit_cast(bf16x8, *(const u16x8*)&ldsU[(wn + j * 16 + rA) * 32 + kA]);
    }
#pragma unroll
    for (int i = 0; i < 4; ++i)
#pragma unroll
      for (int j = 0; j < 4; ++j) {
        ag[i][j] = __builtin_amdgcn_mfma_f32_16x16x32_bf16(a[i], bg[j], ag[i][j], 0, 0, 0);
        au[i][j] = __builtin_amdgcn_mfma_f32_16x16x32_bf16(a[i], bu[j], au[i][j], 0, 0, 0);
      }
    __syncthreads();
  }
  // epilogue: h = silu(g)*u -> bf16 act[pair][F]
  int q = lane >> 4;   // 0..3
#pragma unroll
  for (int i = 0; i < 4; ++i)
#pragma unroll
    for (int r = 0; r < 4; ++r) {
      int row = wm + i * 16 + q * 4 + r;
      if (row < rowCnt) {
        size_t base = (size_t)(rowStart + row) * 4096 + nb * 128 + wn;
#pragma unroll
        for (int j = 0; j < 4; ++j) {
          float g = ag[i][j][r], u = au[i][j][r];
          float hv = (g / (1.f + expf(-g))) * u;
          act[base + j * 16 + rA] = f2bf(hv);
        }
      }
    }
}

// ---- GEMM2: [rows,4096]x[4096,128] -> weighted atomic scatter into out ----
__global__ __launch_bounds__(256) void k_gemm2(
    const u16* __restrict__ act, const u16* __restrict__ PD,
    const int* __restrict__ hdr, const int* __restrict__ rowTok,
    const float* __restrict__ rowW, float* __restrict__ out) {
  __shared__ u16 ldsA[128 * 32];
  __shared__ u16 ldsB[128 * 32];
  int m = blockIdx.y;
  if (m >= hdr[HDR_TOTALM]) return;
  int e = hdr[HDR_BEXP + m], rowStart = hdr[HDR_BSTART + m], rowCnt = hdr[HDR_BCNT + m];
  int nb = blockIdx.x;           // 0..7 over H
  int tid = threadIdx.x, lane = tid & 63, wid = tid >> 6;
  int wm = (wid & 1) * 64, wn = (wid >> 1) * 64;
  const u16* dT = PD + (((size_t)e * 8 + nb) * 128) * 4096;
  f32x4 acc[4][4] = {};
  int rA = lane & 15, kA = (lane >> 4) * 8;
  for (int kb = 0; kb < 128; ++kb) {
#pragma unroll
    for (int h = 0; h < 2; ++h) {
      int c = wid * 64 + lane + h * 256;
      int row = c >> 2, seg = c & 3;
      int p = rowStart + row; if (p > NPAIR - 1) p = NPAIR - 1;
      gl2lds16(act + (size_t)p * 4096 + kb * 32 + seg * 8, ldsA + (wid * 64 + h * 256) * 8);
      gl2lds16(dT + (size_t)kb * 4096 + (size_t)c * 8, ldsB + (wid * 64 + h * 256) * 8);
    }
    __syncthreads();
    bf16x8 a[4], b[4];
#pragma unroll
    for (int i = 0; i < 4; ++i)
      a[i] = __builtin_bit_cast(bf16x8, *(const u16x8*)&ldsA[(wm + i * 16 + rA) * 32 + kA]);
#pragma unroll
    for (int j = 0; j < 4; ++j)
      b[j] = __builtin_bit_cast(bf16x8, *(const u16x8*)&ldsB[(wn + j * 16 + rA) * 32 + kA]);
#pragma unroll
    for (int i = 0; i < 4; ++i)
#pragma unroll
      for (int j = 0; j < 4; ++j)
        acc[i][j] = __builtin_amdgcn_mfma_f32_16x16x32_bf16(a[i], b[j], acc[i][j], 0, 0, 0);
    __syncthreads();
  }
  int q = lane >> 4;
#pragma unroll
  for (int i = 0; i < 4; ++i)
#pragma unroll
    for (int r = 0; r < 4; ++r) {
      int row = wm + i * 16 + q * 4 + r;
      if (row < rowCnt) {
        int p = rowStart + row;
        int tok = rowTok[p];
        float w = rowW[p];
        size_t base = (size_t)tok * Hdim + nb * 128 + wn;
#pragma unroll
        for (int j = 0; j < 4; ++j)
          atomicAdd(&out[base + j * 16 + rA], w * acc[i][j][r]);
      }
    }
}

extern "C" void kernel_launch(void* const* d_in, const int* in_sizes, int n_in,
                              void* d_out, int out_size, void* d_ws, size_t ws_size,
                              hipStream_t stream) {
  const float* x   = (const float*)d_in[0];
  const float* wg  = (const float*)d_in[1];
  const float* wgp = (const float*)d_in[2];
  const float* wup = (const float*)d_in[3];
  const float* wdp = (const float*)d_in[4];
  float* out = (float*)d_out;

  if (ws_size < WS_NEEDED) { k_sentinel<<<1, 1, 0, stream>>>(out); return; }

  char* ws = (char*)d_ws;
  int*   hdr    = (int*)(ws + WS_HDR);
  int*   tokTop = (int*)(ws + WS_TOKTOP);
  float* tokW   = (float*)(ws + WS_TOKW);
  int*   rowTok = (int*)(ws + WS_ROWTOK);
  float* rowW   = (float*)(ws + WS_ROWW);
  u16*   xg     = (u16*)(ws + WS_XG);
  u16*   PG     = (u16*)(ws + WS_WG);
  u16*   PU     = (u16*)(ws + WS_WU);
  u16*   PD     = (u16*)(ws + WS_WD);
  u16*   act    = (u16*)(ws + WS_ACT);

  hipMemsetAsync(hdr, 0, 4096, stream);
  hipMemsetAsync(out, 0, (size_t)OUT0 * sizeof(float), stream);

  k_pack<<<24576, 256, 0, stream>>>(wgp, wup, wdp, PG, PU, PD);
  k_router<<<NT, 64, 0, stream>>>(x, wg, out + OUT0, hdr, tokTop, tokW);
  k_scan<<<1, 1, 0, stream>>>(hdr);
  k_place<<<32, 256, 0, stream>>>(hdr, tokTop, tokW, rowTok, rowW);
  k_gather<<<4096, 256, 0, stream>>>(x, rowTok, xg);
  k_gemm1<<<dim3(32, 136), 256, 0, stream>>>(xg, PG, PU, hdr, act);
  k_gemm2<<<dim3(8, 136), 256, 0, stream>>>(act, PD, hdr, rowTok, rowW, out);
}

// Round 2
// 1302.844 us; speedup vs baseline: 1.2585x; 1.2585x over previous
//
#include <hip/hip_runtime.h>
#include <stdint.h>

// MoE top-2 SwiGLU FFN, MI355X. fp32 in/out, bf16 MFMA compute.
// B=4 S=2048 H=1024 F=4096 E=8 K=2 -> T=8192 tokens, 16384 pairs.
// R2: gemm1 retiled 128x64 (dual acc 64 AGPR, was 128) + launch_bounds(256,2)
//     to lift occupancy from 1 wave/SIMD to 2. gemm2 pinned at (256,2).

#define Hdim 1024
#define Fdim 4096
#define NE 8
#define NT 8192
#define NPAIR 16384
#define OUT0 (NT * Hdim)   // 8388608 floats, then router_logits [NT,8]

typedef unsigned short u16;
typedef __bf16 bf16x8 __attribute__((ext_vector_type(8)));
typedef unsigned short u16x8 __attribute__((ext_vector_type(8)));
typedef float f32x4 __attribute__((ext_vector_type(4)));

// ---- workspace layout (bytes) ----
#define WS_HDR      0ull
#define WS_TOKTOP   4096ull
#define WS_TOKW     69632ull
#define WS_ROWTOK   135168ull
#define WS_ROWW     200704ull
#define WS_XG       266240ull          // bf16 [16384][1024]
#define WS_WG       33820672ull        // packed bf16 [8][32][32][128][32]
#define WS_WU       100929536ull
#define WS_WD       168038400ull       // packed bf16 [8][8][128][128][32]
#define WS_ACT      235147264ull       // bf16 [16384][4096]
#define WS_NEEDED   369364992ull

// hdr int indices
#define HDR_CNT 0
#define HDR_OFF 8
#define HDR_CUR 16
#define HDR_TOTALM 24
#define HDR_BEXP 32      // 160 slots
#define HDR_BSTART 192
#define HDR_BCNT 352

__device__ __forceinline__ u16 f2bf(float f) {
  union { float f; unsigned int u; } v; v.f = f;
  unsigned int u = v.u;
  u += 0x7fffu + ((u >> 16) & 1u);   // round-to-nearest-even
  return (u16)(u >> 16);
}

// async global->LDS, 16B per lane. lds base must be wave-uniform; HW adds lane*16.
__device__ __forceinline__ void gl2lds16(const void* g, void* l) {
  __builtin_amdgcn_global_load_lds(
      (__attribute__((address_space(1))) void*)(uintptr_t)g,
      (__attribute__((address_space(3))) void*)(uint32_t)(uintptr_t)l,
      16, 0, 0);
}

__global__ void k_sentinel(float* out) { out[0] = 3.0e8f; }

// ---- pack: fp32 [K][N] -> bf16 tiles [nb][kb][128][32], contiguous 8KB each ----
__global__ void k_pack(const float* __restrict__ wgp, const float* __restrict__ wup,
                       const float* __restrict__ wdp, u16* __restrict__ PG,
                       u16* __restrict__ PU, u16* __restrict__ PD) {
  __shared__ float lds[32 * 129];
  int tile = blockIdx.x;
  int tensor = tile >> 13;     // 8192 tiles per tensor
  int rem = tile & 8191;
  const float* src; u16* dst; int rowStride;
  int e = rem >> 10, r2 = rem & 1023;
  if (tensor == 0) {
    int nb = r2 >> 5, kb = r2 & 31;
    src = wgp + ((size_t)e * 1024 + kb * 32) * 4096 + nb * 128;
    rowStride = 4096; dst = PG + (size_t)rem * 4096;
  } else if (tensor == 1) {
    int nb = r2 >> 5, kb = r2 & 31;
    src = wup + ((size_t)e * 1024 + kb * 32) * 4096 + nb * 128;
    rowStride = 4096; dst = PU + (size_t)rem * 4096;
  } else {
    int nb = r2 >> 7, kb = r2 & 127;
    src = wdp + ((size_t)e * 4096 + kb * 32) * 1024 + nb * 128;
    rowStride = 1024; dst = PD + (size_t)rem * 4096;
  }
  int tid = threadIdx.x;
  for (int h = 0; h < 4; ++h) {
    int c = tid + h * 256;          // 1024 float4 chunks
    int k = c >> 5, n = (c & 31) * 4;
    f32x4 v = *(const f32x4*)(src + (size_t)k * rowStride + n);
    lds[k * 129 + n + 0] = v[0];
    lds[k * 129 + n + 1] = v[1];
    lds[k * 129 + n + 2] = v[2];
    lds[k * 129 + n + 3] = v[3];
  }
  __syncthreads();
  for (int h = 0; h < 2; ++h) {
    int c = tid + h * 256;          // 512 16B chunks of dst
    int ni = c >> 2, ki0 = (c & 3) * 8;
    u16x8 o;
#pragma unroll
    for (int j = 0; j < 8; ++j) o[j] = f2bf(lds[(ki0 + j) * 129 + ni]);
    *(u16x8*)(dst + c * 8) = o;
  }
}

// ---- router: logits, softmax, top-2, counts ----
__global__ void k_router(const float* __restrict__ x, const float* __restrict__ wg,
                         float* __restrict__ logits, int* __restrict__ hdr,
                         int* __restrict__ tokTop, float* __restrict__ tokW) {
  int t = blockIdx.x;
  int lane = threadIdx.x;   // 64 threads
  float acc[NE] = {0.f, 0.f, 0.f, 0.f, 0.f, 0.f, 0.f, 0.f};
  const float* xr = x + (size_t)t * Hdim + lane * 16;
#pragma unroll
  for (int j4 = 0; j4 < 4; ++j4) {
    f32x4 xv = *(const f32x4*)(xr + j4 * 4);
    int k0 = lane * 16 + j4 * 4;
#pragma unroll
    for (int kk = 0; kk < 4; ++kk) {
      f32x4 w0 = *(const f32x4*)(wg + (size_t)(k0 + kk) * 8);
      f32x4 w1 = *(const f32x4*)(wg + (size_t)(k0 + kk) * 8 + 4);
      float xs = xv[kk];
      acc[0] += xs * w0[0]; acc[1] += xs * w0[1]; acc[2] += xs * w0[2]; acc[3] += xs * w0[3];
      acc[4] += xs * w1[0]; acc[5] += xs * w1[1]; acc[6] += xs * w1[2]; acc[7] += xs * w1[3];
    }
  }
#pragma unroll
  for (int off = 32; off > 0; off >>= 1)
#pragma unroll
    for (int e = 0; e < NE; ++e) acc[e] += __shfl_xor(acc[e], off, 64);
  if (lane < NE) logits[(size_t)t * NE + lane] = acc[lane];
  if (lane == 0) {
    float m = acc[0];
#pragma unroll
    for (int e = 1; e < NE; ++e) m = fmaxf(m, acc[e]);
    float p[NE];
#pragma unroll
    for (int e = 0; e < NE; ++e) p[e] = expf(acc[e] - m);
    int i1 = 0; float p1 = p[0];
#pragma unroll
    for (int e = 1; e < NE; ++e) if (p[e] > p1) { p1 = p[e]; i1 = e; }
    int i2 = -1; float p2 = -1.f;
#pragma unroll
    for (int e = 0; e < NE; ++e) if (e != i1 && p[e] > p2) { p2 = p[e]; i2 = e; }
    float s = p1 + p2;
    tokTop[t * 2] = i1; tokTop[t * 2 + 1] = i2;
    tokW[t * 2] = p1 / s; tokW[t * 2 + 1] = p2 / s;
    atomicAdd(&hdr[HDR_CNT + i1], 1);
    atomicAdd(&hdr[HDR_CNT + i2], 1);
  }
}

// ---- scan: expert offsets + M-block map (<=136 blocks) ----
__global__ void k_scan(int* hdr) {
  if (threadIdx.x != 0 || blockIdx.x != 0) return;
  int cum = 0, mb = 0;
  for (int e = 0; e < NE; ++e) {
    hdr[HDR_OFF + e] = cum;
    int c = hdr[HDR_CNT + e];
    int nb = (c + 127) >> 7;
    for (int b = 0; b < nb; ++b) {
      hdr[HDR_BEXP + mb] = e;
      hdr[HDR_BSTART + mb] = cum + b * 128;
      int rc = c - b * 128; if (rc > 128) rc = 128;
      hdr[HDR_BCNT + mb] = rc;
      ++mb;
    }
    cum += c;
  }
  hdr[HDR_TOTALM] = mb;
}

// ---- place pairs into compact per-expert segments ----
__global__ void k_place(int* __restrict__ hdr, const int* __restrict__ tokTop,
                        const float* __restrict__ tokW, int* __restrict__ rowTok,
                        float* __restrict__ rowW) {
  int t = blockIdx.x * 256 + threadIdx.x;
  if (t >= NT) return;
#pragma unroll
  for (int k = 0; k < 2; ++k) {
    int e = tokTop[t * 2 + k];
    int pos = hdr[HDR_OFF + e] + atomicAdd(&hdr[HDR_CUR + e], 1);
    rowTok[pos] = t;
    rowW[pos] = tokW[t * 2 + k];
  }
}

// ---- gather x rows -> bf16 xg[pair][1024] ----
__global__ void k_gather(const float* __restrict__ x, const int* __restrict__ rowTok,
                         u16* __restrict__ xg) {
  int wid = threadIdx.x >> 6, lane = threadIdx.x & 63;
  int p = blockIdx.x * 4 + wid;
  int tok = rowTok[p];
  const float* src = x + (size_t)tok * Hdim;
  u16* dst = xg + (size_t)p * Hdim;
#pragma unroll
  for (int it = 0; it < 2; ++it) {
    int b = it * 512 + lane * 8;
    f32x4 a = *(const f32x4*)(src + b);
    f32x4 c = *(const f32x4*)(src + b + 4);
    u16x8 o;
    o[0] = f2bf(a[0]); o[1] = f2bf(a[1]); o[2] = f2bf(a[2]); o[3] = f2bf(a[3]);
    o[4] = f2bf(c[0]); o[5] = f2bf(c[1]); o[6] = f2bf(c[2]); o[7] = f2bf(c[3]);
    *(u16x8*)(dst + b) = o;
  }
}

// ---- GEMM1: [rows,1024]x[1024,64] dual (gate & up), fused SiLU*up -> act bf16 ----
// Block tile 128(M) x 64(N); 4 waves, each 64x32 dual => 64 AGPR accumulators.
__global__ __launch_bounds__(256, 2) void k_gemm1(
    const u16* __restrict__ xg, const u16* __restrict__ PG, const u16* __restrict__ PU,
    const int* __restrict__ hdr, u16* __restrict__ act) {
  __shared__ u16 ldsA[128 * 32];   // 8 KB
  __shared__ u16 ldsG[64 * 32];    // 4 KB
  __shared__ u16 ldsU[64 * 32];    // 4 KB
  int m = blockIdx.y;
  if (m >= hdr[HDR_TOTALM]) return;
  int e = hdr[HDR_BEXP + m], rowStart = hdr[HDR_BSTART + m], rowCnt = hdr[HDR_BCNT + m];
  int nb = blockIdx.x;             // 0..63 over F in 64-col tiles
  int tid = threadIdx.x, lane = tid & 63, wid = tid >> 6;
  int wm = (wid & 1) * 64, wn = (wid >> 1) * 32;
  // packed tile = [128 n][32 k]; 64-row half is contiguous 2048 elems
  size_t tileBase = (size_t)(e * 1024 + (nb >> 1) * 32) * 4096 + (size_t)(nb & 1) * 2048;
  const u16* gT = PG + tileBase;
  const u16* uT = PU + tileBase;
  f32x4 ag[4][2] = {};
  f32x4 au[4][2] = {};
  int rA = lane & 15, kA = (lane >> 4) * 8;
  for (int kb = 0; kb < 32; ++kb) {
    // A: 512 chunks (128 rows x 4 segs), 2 per thread
#pragma unroll
    for (int h = 0; h < 2; ++h) {
      int c = wid * 64 + lane + h * 256;
      int row = c >> 2, seg = c & 3;
      int p = rowStart + row; if (p > NPAIR - 1) p = NPAIR - 1;
      gl2lds16(xg + (size_t)p * 1024 + kb * 32 + seg * 8, ldsA + (wid * 64 + h * 256) * 8);
    }
    // G/U: 256 chunks each (64 rows x 4 segs), contiguous in both src and dst
    {
      int c = wid * 64 + lane;
      gl2lds16(gT + (size_t)kb * 4096 + (size_t)c * 8, ldsG + (wid * 64) * 8);
      gl2lds16(uT + (size_t)kb * 4096 + (size_t)c * 8, ldsU + (wid * 64) * 8);
    }
    __syncthreads();
    bf16x8 a[4], bg[2], bu[2];
#pragma unroll
    for (int i = 0; i < 4; ++i)
      a[i] = __builtin_bit_cast(bf16x8, *(const u16x8*)&ldsA[(wm + i * 16 + rA) * 32 + kA]);
#pragma unroll
    for (int j = 0; j < 2; ++j) {
      bg[j] = __builtin_bit_cast(bf16x8, *(const u16x8*)&ldsG[(wn + j * 16 + rA) * 32 + kA]);
      bu[j] = __builtin_bit_cast(bf16x8, *(const u16x8*)&ldsU[(wn + j * 16 + rA) * 32 + kA]);
    }
#pragma unroll
    for (int i = 0; i < 4; ++i)
#pragma unroll
      for (int j = 0; j < 2; ++j) {
        ag[i][j] = __builtin_amdgcn_mfma_f32_16x16x32_bf16(a[i], bg[j], ag[i][j], 0, 0, 0);
        au[i][j] = __builtin_amdgcn_mfma_f32_16x16x32_bf16(a[i], bu[j], au[i][j], 0, 0, 0);
      }
    __syncthreads();
  }
  // epilogue: h = silu(g)*u -> bf16 act[pair][F]
  int q = lane >> 4;   // 0..3
#pragma unroll
  for (int i = 0; i < 4; ++i)
#pragma unroll
    for (int r = 0; r < 4; ++r) {
      int row = wm + i * 16 + q * 4 + r;
      if (row < rowCnt) {
        size_t base = (size_t)(rowStart + row) * 4096 + nb * 64 + wn;
#pragma unroll
        for (int j = 0; j < 2; ++j) {
          float g = ag[i][j][r], u = au[i][j][r];
          float hv = (g / (1.f + expf(-g))) * u;
          act[base + j * 16 + rA] = f2bf(hv);
        }
      }
    }
}

// ---- GEMM2: [rows,4096]x[4096,128] -> weighted atomic scatter into out ----
__global__ __launch_bounds__(256, 2) void k_gemm2(
    const u16* __restrict__ act, const u16* __restrict__ PD,
    const int* __restrict__ hdr, const int* __restrict__ rowTok,
    const float* __restrict__ rowW, float* __restrict__ out) {
  __shared__ u16 ldsA[128 * 32];
  __shared__ u16 ldsB[128 * 32];
  int m = blockIdx.y;
  if (m >= hdr[HDR_TOTALM]) return;
  int e = hdr[HDR_BEXP + m], rowStart = hdr[HDR_BSTART + m], rowCnt = hdr[HDR_BCNT + m];
  int nb = blockIdx.x;           // 0..7 over H
  int tid = threadIdx.x, lane = tid & 63, wid = tid >> 6;
  int wm = (wid & 1) * 64, wn = (wid >> 1) * 64;
  const u16* dT = PD + (((size_t)e * 8 + nb) * 128) * 4096;
  f32x4 acc[4][4] = {};
  int rA = lane & 15, kA = (lane >> 4) * 8;
  for (int kb = 0; kb < 128; ++kb) {
#pragma unroll
    for (int h = 0; h < 2; ++h) {
      int c = wid * 64 + lane + h * 256;
      int row = c >> 2, seg = c & 3;
      int p = rowStart + row; if (p > NPAIR - 1) p = NPAIR - 1;
      gl2lds16(act + (size_t)p * 4096 + kb * 32 + seg * 8, ldsA + (wid * 64 + h * 256) * 8);
      gl2lds16(dT + (size_t)kb * 4096 + (size_t)c * 8, ldsB + (wid * 64 + h * 256) * 8);
    }
    __syncthreads();
    bf16x8 a[4], b[4];
#pragma unroll
    for (int i = 0; i < 4; ++i)
      a[i] = __builtin_bit_cast(bf16x8, *(const u16x8*)&ldsA[(wm + i * 16 + rA) * 32 + kA]);
#pragma unroll
    for (int j = 0; j < 4; ++j)
      b[j] = __builtin_bit_cast(bf16x8, *(const u16x8*)&ldsB[(wn + j * 16 + rA) * 32 + kA]);
#pragma unroll
    for (int i = 0; i < 4; ++i)
#pragma unroll
      for (int j = 0; j < 4; ++j)
        acc[i][j] = __builtin_amdgcn_mfma_f32_16x16x32_bf16(a[i], b[j], acc[i][j], 0, 0, 0);
    __syncthreads();
  }
  int q = lane >> 4;
#pragma unroll
  for (int i = 0; i < 4; ++i)
#pragma unroll
    for (int r = 0; r < 4; ++r) {
      int row = wm + i * 16 + q * 4 + r;
      if (row < rowCnt) {
        int p = rowStart + row;
        int tok = rowTok[p];
        float w = rowW[p];
        size_t base = (size_t)tok * Hdim + nb * 128 + wn;
#pragma unroll
        for (int j = 0; j < 4; ++j)
          atomicAdd(&out[base + j * 16 + rA], w * acc[i][j][r]);
      }
    }
}

extern "C" void kernel_launch(void* const* d_in, const int* in_sizes, int n_in,
                              void* d_out, int out_size, void* d_ws, size_t ws_size,
                              hipStream_t stream) {
  const float* x   = (const float*)d_in[0];
  const float* wg  = (const float*)d_in[1];
  const float* wgp = (const float*)d_in[2];
  const float* wup = (const float*)d_in[3];
  const float* wdp = (const float*)d_in[4];
  float* out = (float*)d_out;

  if (ws_size < WS_NEEDED) { k_sentinel<<<1, 1, 0, stream>>>(out); return; }

  char* ws = (char*)d_ws;
  int*   hdr    = (int*)(ws + WS_HDR);
  int*   tokTop = (int*)(ws + WS_TOKTOP);
  float* tokW   = (float*)(ws + WS_TOKW);
  int*   rowTok = (int*)(ws + WS_ROWTOK);
  float* rowW   = (float*)(ws + WS_ROWW);
  u16*   xg     = (u16*)(ws + WS_XG);
  u16*   PG     = (u16*)(ws + WS_WG);
  u16*   PU     = (u16*)(ws + WS_WU);
  u16*   PD     = (u16*)(ws + WS_WD);
  u16*   act    = (u16*)(ws + WS_ACT);

  hipMemsetAsync(hdr, 0, 4096, stream);
  hipMemsetAsync(out, 0, (size_t)OUT0 * sizeof(float), stream);

  k_pack<<<24576, 256, 0, stream>>>(wgp, wup, wdp, PG, PU, PD);
  k_router<<<NT, 64, 0, stream>>>(x, wg, out + OUT0, hdr, tokTop, tokW);
  k_scan<<<1, 1, 0, stream>>>(hdr);
  k_place<<<32, 256, 0, stream>>>(hdr, tokTop, tokW, rowTok, rowW);
  k_gather<<<4096, 256, 0, stream>>>(x, rowTok, xg);
  k_gemm1<<<dim3(64, 136), 256, 0, stream>>>(xg, PG, PU, hdr, act);
  k_gemm2<<<dim3(8, 136), 256, 0, stream>>>(act, PD, hdr, rowTok, rowW, out);
}